// Round 10
// baseline (262.060 us; speedup 1.0000x reference)
//
#include <hip/hip_runtime.h>
#include <stdint.h>

#define B_ 2
#define S_ 2048
#define D_ 1024
#define H_ 16
#define DH 64
#define BS_ (B_*S_)
#define QBLK 128
#define KBLK 128

typedef unsigned short u16;
typedef __attribute__((ext_vector_type(8))) __bf16 bf16x8;
typedef __attribute__((ext_vector_type(4))) float f32x4;

__device__ __forceinline__ u16 f2bf(float f){
  unsigned u = __float_as_uint(f);
  u += 0x7fffu + ((u >> 16) & 1u);   // RNE
  return (u16)(u >> 16);
}
__device__ __forceinline__ float bf2f(u16 v){
  return __uint_as_float(((unsigned)v) << 16);
}

union pk8 { u16 a[8]; uint4 v; };

typedef __attribute__((address_space(1))) const unsigned gas_u32;
typedef __attribute__((address_space(3))) unsigned las_u32;
__device__ __forceinline__ void gload16(const void* g, void* l){
  __builtin_amdgcn_global_load_lds((gas_u32*)g, (las_u32*)l, 16, 0, 0);
}

// ---------------- fp32 -> bf16 convert (4 weight tensors only) ----------------
__global__ __launch_bounds__(256) void cvt_kernel(
    const float* __restrict__ WQ, const float* __restrict__ WK,
    const float* __restrict__ WV, const float* __restrict__ WO,
    u16* wq, u16* wk, u16* wv, u16* wo)
{
  const int b = blockIdx.x;
  const int t = b >> 9;
  const float* s = t==0?WQ:(t==1?WK:(t==2?WV:WO));
  u16* d = t==0?wq:(t==1?wk:(t==2?wv:wo));
  const size_t off = (size_t)(b & 511)*2048;
  const float* sp = s + off + (size_t)threadIdx.x*8;
  f32x4 v0 = __builtin_nontemporal_load((const f32x4*)sp);
  f32x4 v1 = __builtin_nontemporal_load((const f32x4*)(sp + 4));
  pk8 p;
  p.a[0]=f2bf(v0[0]); p.a[1]=f2bf(v0[1]); p.a[2]=f2bf(v0[2]); p.a[3]=f2bf(v0[3]);
  p.a[4]=f2bf(v1[0]); p.a[5]=f2bf(v1[1]); p.a[6]=f2bf(v1[2]); p.a[7]=f2bf(v1[3]);
  *(uint4*)(d + off + (size_t)threadIdx.x*8) = p.v;
}

// ---------------- GEMM core (device) -------------------------------------
// AF32: A is fp32, reg-staged (load early, cvt+ds_write late). else bf16 gload_lds.
template<int F32OUT, int AF32>
__device__ __forceinline__ void gemm_body(
    const void* __restrict__ Ap, const u16* __restrict__ Wt,
    const float* __restrict__ bias, void* __restrict__ Cout,
    int bm, int bn, int N, int K)
{
  const int tid = threadIdx.x, w = tid >> 6, lane = tid & 63;
  const int g = lane >> 4, c16 = lane & 15;
  const int wr = w >> 1, wc = w & 1;
  const int lr = lane >> 3, lg = lane & 7;
  const int gsrc = lg ^ (lr & 7);

  __shared__ alignas(16) u16 at[2][128*64];
  __shared__ alignas(16) u16 bt[2][128*64];

  f32x4 acc[4][4];
  #pragma unroll
  for (int mi = 0; mi < 4; ++mi)
    #pragma unroll
    for (int ni = 0; ni < 4; ++ni) acc[mi][ni] = (f32x4){0.f,0.f,0.f,0.f};

  // fp32 A reg-staging buffers (granule id = tid + i*256; row=id>>3, gi=id&7)
  f32x4 a0[4], a1[4];
  auto loadA = [&](int kt){
    #pragma unroll
    for (int i = 0; i < 4; ++i){
      const int id = tid + i*256, row = id >> 3, gi = id & 7;
      const float* src = (const float*)Ap + (size_t)(bm*128 + row)*K + kt + gi*8;
      a0[i] = __builtin_nontemporal_load((const f32x4*)src);
      a1[i] = __builtin_nontemporal_load((const f32x4*)(src + 4));
    }
  };
  auto writeA = [&](int buf){
    #pragma unroll
    for (int i = 0; i < 4; ++i){
      const int id = tid + i*256, row = id >> 3, gi = id & 7;
      pk8 p;
      p.a[0]=f2bf(a0[i][0]); p.a[1]=f2bf(a0[i][1]); p.a[2]=f2bf(a0[i][2]); p.a[3]=f2bf(a0[i][3]);
      p.a[4]=f2bf(a1[i][0]); p.a[5]=f2bf(a1[i][1]); p.a[6]=f2bf(a1[i][2]); p.a[7]=f2bf(a1[i][3]);
      *(uint4*)(at[buf] + row*64 + ((gi ^ (row & 7)))*8) = p.v;
    }
  };
  auto stageA = [&](int buf, int kt){   // bf16 A via gload_lds
    #pragma unroll
    for (int i = 0; i < 4; ++i){
      const int r = w*32 + i*8 + lr;
      gload16((const u16*)Ap + (size_t)(bm*128 + r)*K + kt + gsrc*8,
              at[buf] + (w*32 + i*8)*64);
    }
  };
  auto stageB = [&](int buf, int kt){
    #pragma unroll
    for (int i = 0; i < 4; ++i){
      const int r = w*32 + i*8 + lr;
      gload16(Wt + (size_t)(bn*128 + r)*K + kt + gsrc*8, bt[buf] + (w*32 + i*8)*64);
    }
  };

  if (AF32){ loadA(0); stageB(0, 0); writeA(0); }
  else     { stageA(0, 0); stageB(0, 0); }
  __syncthreads();
  int cur = 0;
  for (int kt = 0; kt < K; kt += 64){
    const bool more = kt + 64 < K;
    if (more){
      if (AF32) loadA(kt + 64); else stageA(cur ^ 1, kt + 64);
      stageB(cur ^ 1, kt + 64);
    }
    #pragma unroll
    for (int ks = 0; ks < 2; ++ks){
      bf16x8 af[4], bfr[4];
      #pragma unroll
      for (int mi = 0; mi < 4; ++mi){
        const int row = wr*64 + mi*16 + c16;
        af[mi] = *(const bf16x8*)(at[cur] + row*64 + ((ks*4 + g) ^ (row & 7))*8);
      }
      #pragma unroll
      for (int ni = 0; ni < 4; ++ni){
        const int row = wc*64 + ni*16 + c16;
        bfr[ni] = *(const bf16x8*)(bt[cur] + row*64 + ((ks*4 + g) ^ (row & 7))*8);
      }
      #pragma unroll
      for (int mi = 0; mi < 4; ++mi)
        #pragma unroll
        for (int ni = 0; ni < 4; ++ni)
          acc[mi][ni] = __builtin_amdgcn_mfma_f32_16x16x32_bf16(
              af[mi], bfr[ni], acc[mi][ni], 0, 0, 0);
    }
    if (AF32 && more) writeA(cur ^ 1);
    __syncthreads();
    cur ^= 1;
  }

  #pragma unroll
  for (int mi = 0; mi < 4; ++mi){
    const int row0 = bm*128 + wr*64 + mi*16 + g*4;
    #pragma unroll
    for (int ni = 0; ni < 4; ++ni){
      const int col = bn*128 + wc*64 + ni*16 + c16;
      const float bb = bias[col];
      #pragma unroll
      for (int r = 0; r < 4; ++r){
        float v = acc[mi][ni][r] + bb;
        if (F32OUT) __builtin_nontemporal_store(v, (float*)Cout + (size_t)(row0 + r)*N + col);
        else        ((u16*)Cout)[(size_t)(row0 + r)*N + col] = f2bf(v);
      }
    }
  }
}

__global__ __launch_bounds__(256) void qkv_gemm_kernel(
    const float* __restrict__ Q, const float* __restrict__ K, const float* __restrict__ V,
    const u16* __restrict__ W0, const u16* __restrict__ W1, const u16* __restrict__ W2,
    const float* __restrict__ b0, const float* __restrict__ b1, const float* __restrict__ b2,
    u16* C0, u16* C1, u16* C2)
{
  const int t = blockIdx.z;
  const float* A = t==0?Q:(t==1?K:V);
  const u16* W = t==0?W0:(t==1?W1:W2);
  const float* bb = t==0?b0:(t==1?b1:b2);
  u16* C = t==0?C0:(t==1?C1:C2);
  gemm_body<0,1>(A, W, bb, C, blockIdx.x, blockIdx.y, D_, D_);
}

__global__ __launch_bounds__(256) void out_gemm_kernel(
    const u16* __restrict__ A, const u16* __restrict__ W,
    const float* __restrict__ bias, float* __restrict__ C)
{
  gemm_body<1,0>(A, W, bias, C, blockIdx.x, blockIdx.y, D_, D_);
}

// ---------------- per-head V transpose: vtb[bh][d][k] = vb[bh][k][d] ----------------
__global__ __launch_bounds__(256) void vtrans_kernel(
    const u16* __restrict__ vb, u16* __restrict__ vtb)
{
  const int kt = blockIdx.x, bh = blockIdx.y;
  __shared__ alignas(16) u16 t[64][80];
  const int tid = threadIdx.x;
  const u16* slab = vb + (size_t)bh*S_*DH + (size_t)kt*64*DH;
  #pragma unroll
  for (int j = 0; j < 2; ++j){
    const int r = j*32 + (tid >> 3), c = (tid & 7)*8;
    *(bf16x8*)(&t[r][c]) = *(const bf16x8*)(slab + (size_t)r*DH + c);
  }
  __syncthreads();
  u16* oslab = vtb + (size_t)bh*DH*S_ + (size_t)kt*64;
  #pragma unroll
  for (int j = 0; j < 2; ++j){
    const int dd = j*32 + (tid >> 3), k8 = (tid & 7)*8;
    pk8 u;
    #pragma unroll
    for (int e = 0; e < 8; ++e) u.a[e] = t[k8 + e][dd];
    *(uint4*)(oslab + (size_t)dd*S_ + k8) = u.v;
  }
}

// ---------------- fused attention: QBLK=128, 8 waves, nt dist writes ------
__global__ __launch_bounds__(512, 4) void attn_kernel(
    const u16* __restrict__ qb, const u16* __restrict__ kb,
    const u16* __restrict__ vtb, float* __restrict__ dist,
    u16* __restrict__ attnb)
{
  // bijective remap: XCD (blockIdx.x%8) owns 4 consecutive heads
  const int vb_ = (blockIdx.x & 7)*64 + (blockIdx.x >> 3);
  const int qblk = vb_ & 15, bh = vb_ >> 4;

  const int tid = threadIdx.x, w = tid >> 6, lane = tid & 63;
  const int g = lane >> 4, c16 = lane & 15;
  const int lr = lane >> 3, lg = lane & 7;
  const int gsrc = lg ^ (lr & 7);
  const int lr4 = lane >> 4, lg4 = lane & 15;

  __shared__ alignas(16) u16 klds[128*64];    // 16 KB
  __shared__ alignas(16) u16 vtlds[64*128];   // 16 KB
  __shared__ alignas(16) u16 plds[8*16*128];  // 32 KB (4 KB per warp)

  const u16* qsl = qb  + (size_t)bh*S_*DH;
  const u16* ksl = kb  + (size_t)bh*S_*DH;
  const u16* vsl = vtb + (size_t)bh*DH*S_;

  const int q0 = qblk*QBLK + w*16;
  bf16x8 qf[2];
  #pragma unroll
  for (int ks = 0; ks < 2; ++ks)
    qf[ks] = *(const bf16x8*)(qsl + (size_t)(q0 + c16)*DH + ks*32 + g*8);

  const float cl = (1.0f/32.0f)*1.44269504f;   // scale * log2(e)
  float sum = 0.f;

  auto stageK = [&](int kt){
    #pragma unroll
    for (int i = 0; i < 2; ++i){
      const int r = w*16 + i*8 + lr;
      gload16(ksl + (size_t)(kt + r)*DH + gsrc*8, klds + (w*16 + i*8)*64);
    }
  };
  auto stageV = [&](int kt){
    #pragma unroll
    for (int i = 0; i < 2; ++i){
      const int d = w*8 + i*4 + lr4;
      const int gs = lg4 ^ (d & 15);
      gload16(vsl + (size_t)d*S_ + kt + gs*8, vtlds + (w*8 + i*4)*128);
    }
  };

  // ---- pass 1: denominators ----
  for (int kt = 0; kt < S_; kt += KBLK){
    stageK(kt);
    __syncthreads();
    #pragma unroll
    for (int ng = 0; ng < 2; ++ng){
      bf16x8 kf[4][2];
      f32x4 s[4];
      #pragma unroll
      for (int j = 0; j < 4; ++j){
        const int krow = (ng*4 + j)*16 + c16;
        kf[j][0] = *(const bf16x8*)(klds + krow*64 + ((0 + g) ^ (krow & 7))*8);
        kf[j][1] = *(const bf16x8*)(klds + krow*64 + ((4 + g) ^ (krow & 7))*8);
      }
      __builtin_amdgcn_s_setprio(1);
      #pragma unroll
      for (int j = 0; j < 4; ++j){
        s[j] = (f32x4){0.f,0.f,0.f,0.f};
        s[j] = __builtin_amdgcn_mfma_f32_16x16x32_bf16(kf[j][0], qf[0], s[j], 0, 0, 0);
      }
      #pragma unroll
      for (int j = 0; j < 4; ++j)
        s[j] = __builtin_amdgcn_mfma_f32_16x16x32_bf16(kf[j][1], qf[1], s[j], 0, 0, 0);
      __builtin_amdgcn_s_setprio(0);
      #pragma unroll
      for (int j = 0; j < 4; ++j)
        #pragma unroll
        for (int r = 0; r < 4; ++r) sum += exp2f(s[j][r]*cl);
    }
    __syncthreads();
  }
  sum += __shfl_xor(sum, 16, 64);
  sum += __shfl_xor(sum, 32, 64);
  const float inv = 1.0f/sum;

  f32x4 oacc[4];
  #pragma unroll
  for (int n2 = 0; n2 < 4; ++n2) oacc[n2] = (f32x4){0.f,0.f,0.f,0.f};

  float* drow0 = dist + ((size_t)bh*S_ + q0)*S_;
  const int rlane = lane >> 5;          // 0/1: row within pair
  const int chunk = lane & 31;          // 4-float chunk within 128-col segment
  const int slotc = chunk >> 1, halfc = (chunk & 1)*4;

  // ---- pass 2: P -> plds, nt dist write (early), then PV ----
  for (int kt = 0; kt < S_; kt += KBLK){
    stageK(kt);
    stageV(kt);
    __syncthreads();
    #pragma unroll
    for (int ng = 0; ng < 2; ++ng){
      bf16x8 kf[4][2];
      f32x4 s[4];
      #pragma unroll
      for (int j = 0; j < 4; ++j){
        const int krow = (ng*4 + j)*16 + c16;
        kf[j][0] = *(const bf16x8*)(klds + krow*64 + ((0 + g) ^ (krow & 7))*8);
        kf[j][1] = *(const bf16x8*)(klds + krow*64 + ((4 + g) ^ (krow & 7))*8);
      }
      __builtin_amdgcn_s_setprio(1);
      #pragma unroll
      for (int j = 0; j < 4; ++j){
        s[j] = (f32x4){0.f,0.f,0.f,0.f};
        s[j] = __builtin_amdgcn_mfma_f32_16x16x32_bf16(kf[j][0], qf[0], s[j], 0, 0, 0);
      }
      #pragma unroll
      for (int j = 0; j < 4; ++j)
        s[j] = __builtin_amdgcn_mfma_f32_16x16x32_bf16(kf[j][1], qf[1], s[j], 0, 0, 0);
      __builtin_amdgcn_s_setprio(0);
      #pragma unroll
      for (int j = 0; j < 4; ++j){
        const int n = ng*4 + j;
        float p0 = exp2f(s[j][0]*cl)*inv, p1 = exp2f(s[j][1]*cl)*inv;
        float p2 = exp2f(s[j][2]*cl)*inv, p3 = exp2f(s[j][3]*cl)*inv;
        const int col = n*16 + g*4;
        const int slot = (col >> 3) ^ c16;
        unsigned lo = (unsigned)f2bf(p0) | ((unsigned)f2bf(p1) << 16);
        unsigned hi = (unsigned)f2bf(p2) | ((unsigned)f2bf(p3) << 16);
        uint2 pk2; pk2.x = lo; pk2.y = hi;
        *(uint2*)(plds + w*2048 + c16*128 + slot*8 + (g & 1)*4) = pk2;
      }
    }
    // coalesced nt dist write from plds — before PV so stores drain under MFMA
    #pragma unroll
    for (int it = 0; it < 8; ++it){
      const int row = it*2 + rlane;
      const u16* src = plds + w*2048 + row*128 + (slotc ^ row)*8 + halfc;
      uint2 pv = *(const uint2*)src;
      f32x4 o;
      o[0] = bf2f((u16)(pv.x & 0xffffu));
      o[1] = bf2f((u16)(pv.x >> 16));
      o[2] = bf2f((u16)(pv.y & 0xffffu));
      o[3] = bf2f((u16)(pv.y >> 16));
      __builtin_nontemporal_store(o, (f32x4*)(drow0 + (size_t)row*S_ + kt + chunk*4));
    }
    // PV: oacc += P @ V
    #pragma unroll
    for (int kc = 0; kc < 4; ++kc){
      bf16x8 pf = *(const bf16x8*)(plds + w*2048 + c16*128 + ((kc*4 + g) ^ c16)*8);
      __builtin_amdgcn_s_setprio(1);
      #pragma unroll
      for (int n2 = 0; n2 < 4; ++n2){
        const int d = n2*16 + c16;
        bf16x8 vf = *(const bf16x8*)(vtlds + d*128 + ((kc*4 + g) ^ (d & 15))*8);
        oacc[n2] = __builtin_amdgcn_mfma_f32_16x16x32_bf16(pf, vf, oacc[n2], 0, 0, 0);
      }
      __builtin_amdgcn_s_setprio(0);
    }
    __syncthreads();
  }

  u16* asl = attnb + (size_t)bh*S_*DH;
  #pragma unroll
  for (int n2 = 0; n2 < 4; ++n2)
    #pragma unroll
    for (int r = 0; r < 4; ++r)
      __builtin_nontemporal_store(f2bf(oacc[n2][r]),
          asl + (size_t)(q0 + g*4 + r)*DH + n2*16 + c16);
}

// ---------------- launch ----------------
extern "C" void kernel_launch(void* const* d_in, const int* in_sizes, int n_in,
                              void* d_out, int out_size, void* d_ws, size_t ws_size,
                              hipStream_t stream)
{
  const float* Q  = (const float*)d_in[0];
  const float* K  = (const float*)d_in[1];
  const float* V  = (const float*)d_in[2];
  const float* WQ = (const float*)d_in[3]; const float* bQ = (const float*)d_in[4];
  const float* WK = (const float*)d_in[5]; const float* bK = (const float*)d_in[6];
  const float* WV = (const float*)d_in[7]; const float* bV = (const float*)d_in[8];
  const float* WO = (const float*)d_in[9]; const float* bO = (const float*)d_in[10];

  float* out  = (float*)d_out;
  float* dist = out + (size_t)BS_*D_;

  char* ws = (char*)d_ws;
  u16* qb    = (u16*)(ws);
  u16* kb    = (u16*)(ws + (8u<<20));
  u16* vb    = (u16*)(ws + (16u<<20));
  u16* vtb   = (u16*)(ws + (24u<<20));
  u16* attnb = (u16*)(ws + (32u<<20));
  u16* wqb   = (u16*)(ws + (40u<<20));
  u16* wkb   = (u16*)(ws + (42u<<20));
  u16* wvb   = (u16*)(ws + (44u<<20));
  u16* wob   = (u16*)(ws + (46u<<20));

  cvt_kernel<<<2048, 256, 0, stream>>>(WQ, WK, WV, WO, wqb, wkb, wvb, wob);

  qkv_gemm_kernel<<<dim3(BS_/128, D_/128, 3), 256, 0, stream>>>(
      Q, K, V, wqb, wkb, wvb, bQ, bK, bV, qb, kb, vb);

  vtrans_kernel<<<dim3(S_/64, B_*H_), 256, 0, stream>>>(vb, vtb);

  attn_kernel<<<dim3((S_/QBLK)*(B_*H_)), 512, 0, stream>>>(qb, kb, vtb, dist, attnb);

  out_gemm_kernel<<<dim3(BS_/128, D_/128), 256, 0, stream>>>(attnb, wob, bO, out);
}

// Round 11
// 237.559 us; speedup vs baseline: 1.1031x; 1.1031x over previous
//
#include <hip/hip_runtime.h>
#include <stdint.h>

#define B_ 2
#define S_ 2048
#define D_ 1024
#define H_ 16
#define DH 64
#define BS_ (B_*S_)
#define QBLK 128
#define KBLK 128

typedef unsigned short u16;
typedef __attribute__((ext_vector_type(8))) __bf16 bf16x8;
typedef __attribute__((ext_vector_type(4))) float f32x4;

__device__ __forceinline__ u16 f2bf(float f){
  unsigned u = __float_as_uint(f);
  u += 0x7fffu + ((u >> 16) & 1u);   // RNE
  return (u16)(u >> 16);
}
__device__ __forceinline__ float bf2f(u16 v){
  return __uint_as_float(((unsigned)v) << 16);
}

union pk8 { u16 a[8]; uint4 v; };

typedef __attribute__((address_space(1))) const unsigned gas_u32;
typedef __attribute__((address_space(3))) unsigned las_u32;
__device__ __forceinline__ void gload16(const void* g, void* l){
  __builtin_amdgcn_global_load_lds((gas_u32*)g, (las_u32*)l, 16, 0, 0);
}

// ---------------- fp32 -> bf16 convert (4 weight tensors only) ----------------
__global__ __launch_bounds__(256) void cvt_kernel(
    const float* __restrict__ WQ, const float* __restrict__ WK,
    const float* __restrict__ WV, const float* __restrict__ WO,
    u16* wq, u16* wk, u16* wv, u16* wo)
{
  const int b = blockIdx.x;
  const int t = b >> 9;
  const float* s = t==0?WQ:(t==1?WK:(t==2?WV:WO));
  u16* d = t==0?wq:(t==1?wk:(t==2?wv:wo));
  const size_t off = (size_t)(b & 511)*2048;
  const float* sp = s + off + (size_t)threadIdx.x*8;
  f32x4 v0 = __builtin_nontemporal_load((const f32x4*)sp);
  f32x4 v1 = __builtin_nontemporal_load((const f32x4*)(sp + 4));
  pk8 p;
  p.a[0]=f2bf(v0[0]); p.a[1]=f2bf(v0[1]); p.a[2]=f2bf(v0[2]); p.a[3]=f2bf(v0[3]);
  p.a[4]=f2bf(v1[0]); p.a[5]=f2bf(v1[1]); p.a[6]=f2bf(v1[2]); p.a[7]=f2bf(v1[3]);
  *(uint4*)(d + off + (size_t)threadIdx.x*8) = p.v;
}

// ---------------- GEMM core (device) -------------------------------------
// AF32: A is fp32, reg-staged with CACHED loads (A-panels are reused by the
// 8 bn-blocks on the same XCD — nt here cost +40us in R10). else bf16 gload_lds.
template<int F32OUT, int AF32>
__device__ __forceinline__ void gemm_body(
    const void* __restrict__ Ap, const u16* __restrict__ Wt,
    const float* __restrict__ bias, void* __restrict__ Cout,
    int bm, int bn, int N, int K)
{
  const int tid = threadIdx.x, w = tid >> 6, lane = tid & 63;
  const int g = lane >> 4, c16 = lane & 15;
  const int wr = w >> 1, wc = w & 1;
  const int lr = lane >> 3, lg = lane & 7;
  const int gsrc = lg ^ (lr & 7);

  __shared__ alignas(16) u16 at[2][128*64];
  __shared__ alignas(16) u16 bt[2][128*64];

  f32x4 acc[4][4];
  #pragma unroll
  for (int mi = 0; mi < 4; ++mi)
    #pragma unroll
    for (int ni = 0; ni < 4; ++ni) acc[mi][ni] = (f32x4){0.f,0.f,0.f,0.f};

  // fp32 A reg-staging buffers (granule id = tid + i*256; row=id>>3, gi=id&7)
  f32x4 a0[4], a1[4];
  auto loadA = [&](int kt){
    #pragma unroll
    for (int i = 0; i < 4; ++i){
      const int id = tid + i*256, row = id >> 3, gi = id & 7;
      const float* src = (const float*)Ap + (size_t)(bm*128 + row)*K + kt + gi*8;
      a0[i] = *(const f32x4*)src;          // cached: panel reused by 8 blocks
      a1[i] = *(const f32x4*)(src + 4);
    }
  };
  auto writeA = [&](int buf){
    #pragma unroll
    for (int i = 0; i < 4; ++i){
      const int id = tid + i*256, row = id >> 3, gi = id & 7;
      pk8 p;
      p.a[0]=f2bf(a0[i][0]); p.a[1]=f2bf(a0[i][1]); p.a[2]=f2bf(a0[i][2]); p.a[3]=f2bf(a0[i][3]);
      p.a[4]=f2bf(a1[i][0]); p.a[5]=f2bf(a1[i][1]); p.a[6]=f2bf(a1[i][2]); p.a[7]=f2bf(a1[i][3]);
      *(uint4*)(at[buf] + row*64 + ((gi ^ (row & 7)))*8) = p.v;
    }
  };
  auto stageA = [&](int buf, int kt){   // bf16 A via gload_lds
    #pragma unroll
    for (int i = 0; i < 4; ++i){
      const int r = w*32 + i*8 + lr;
      gload16((const u16*)Ap + (size_t)(bm*128 + r)*K + kt + gsrc*8,
              at[buf] + (w*32 + i*8)*64);
    }
  };
  auto stageB = [&](int buf, int kt){
    #pragma unroll
    for (int i = 0; i < 4; ++i){
      const int r = w*32 + i*8 + lr;
      gload16(Wt + (size_t)(bn*128 + r)*K + kt + gsrc*8, bt[buf] + (w*32 + i*8)*64);
    }
  };

  if (AF32){ loadA(0); stageB(0, 0); writeA(0); }
  else     { stageA(0, 0); stageB(0, 0); }
  __syncthreads();
  int cur = 0;
  for (int kt = 0; kt < K; kt += 64){
    const bool more = kt + 64 < K;
    if (more){
      if (AF32) loadA(kt + 64); else stageA(cur ^ 1, kt + 64);
      stageB(cur ^ 1, kt + 64);
    }
    #pragma unroll
    for (int ks = 0; ks < 2; ++ks){
      bf16x8 af[4], bfr[4];
      #pragma unroll
      for (int mi = 0; mi < 4; ++mi){
        const int row = wr*64 + mi*16 + c16;
        af[mi] = *(const bf16x8*)(at[cur] + row*64 + ((ks*4 + g) ^ (row & 7))*8);
      }
      #pragma unroll
      for (int ni = 0; ni < 4; ++ni){
        const int row = wc*64 + ni*16 + c16;
        bfr[ni] = *(const bf16x8*)(bt[cur] + row*64 + ((ks*4 + g) ^ (row & 7))*8);
      }
      #pragma unroll
      for (int mi = 0; mi < 4; ++mi)
        #pragma unroll
        for (int ni = 0; ni < 4; ++ni)
          acc[mi][ni] = __builtin_amdgcn_mfma_f32_16x16x32_bf16(
              af[mi], bfr[ni], acc[mi][ni], 0, 0, 0);
    }
    if (AF32 && more) writeA(cur ^ 1);
    __syncthreads();
    cur ^= 1;
  }

  #pragma unroll
  for (int mi = 0; mi < 4; ++mi){
    const int row0 = bm*128 + wr*64 + mi*16 + g*4;
    #pragma unroll
    for (int ni = 0; ni < 4; ++ni){
      const int col = bn*128 + wc*64 + ni*16 + c16;
      const float bb = bias[col];
      #pragma unroll
      for (int r = 0; r < 4; ++r){
        float v = acc[mi][ni][r] + bb;
        if (F32OUT) __builtin_nontemporal_store(v, (float*)Cout + (size_t)(row0 + r)*N + col);
        else        ((u16*)Cout)[(size_t)(row0 + r)*N + col] = f2bf(v);
      }
    }
  }
}

__global__ __launch_bounds__(256) void qkv_gemm_kernel(
    const float* __restrict__ Q, const float* __restrict__ K, const float* __restrict__ V,
    const u16* __restrict__ W0, const u16* __restrict__ W1, const u16* __restrict__ W2,
    const float* __restrict__ b0, const float* __restrict__ b1, const float* __restrict__ b2,
    u16* C0, u16* C1, u16* C2)
{
  const int t = blockIdx.z;
  const float* A = t==0?Q:(t==1?K:V);
  const u16* W = t==0?W0:(t==1?W1:W2);
  const float* bb = t==0?b0:(t==1?b1:b2);
  u16* C = t==0?C0:(t==1?C1:C2);
  gemm_body<0,1>(A, W, bb, C, blockIdx.x, blockIdx.y, D_, D_);
}

__global__ __launch_bounds__(256) void out_gemm_kernel(
    const u16* __restrict__ A, const u16* __restrict__ W,
    const float* __restrict__ bias, float* __restrict__ C)
{
  gemm_body<1,0>(A, W, bias, C, blockIdx.x, blockIdx.y, D_, D_);
}

// ---------------- per-head V transpose: vtb[bh][d][k] = vb[bh][k][d] ----------------
__global__ __launch_bounds__(256) void vtrans_kernel(
    const u16* __restrict__ vb, u16* __restrict__ vtb)
{
  const int kt = blockIdx.x, bh = blockIdx.y;
  __shared__ alignas(16) u16 t[64][80];
  const int tid = threadIdx.x;
  const u16* slab = vb + (size_t)bh*S_*DH + (size_t)kt*64*DH;
  #pragma unroll
  for (int j = 0; j < 2; ++j){
    const int r = j*32 + (tid >> 3), c = (tid & 7)*8;
    *(bf16x8*)(&t[r][c]) = *(const bf16x8*)(slab + (size_t)r*DH + c);
  }
  __syncthreads();
  u16* oslab = vtb + (size_t)bh*DH*S_ + (size_t)kt*64;
  #pragma unroll
  for (int j = 0; j < 2; ++j){
    const int dd = j*32 + (tid >> 3), k8 = (tid & 7)*8;
    pk8 u;
    #pragma unroll
    for (int e = 0; e < 8; ++e) u.a[e] = t[k8 + e][dd];
    *(uint4*)(oslab + (size_t)dd*S_ + k8) = u.v;
  }
}

// ---------------- fused attention: QBLK=128, 8 waves, nt dist writes ------
__global__ __launch_bounds__(512, 4) void attn_kernel(
    const u16* __restrict__ qb, const u16* __restrict__ kb,
    const u16* __restrict__ vtb, float* __restrict__ dist,
    u16* __restrict__ attnb)
{
  // bijective remap: XCD (blockIdx.x%8) owns 4 consecutive heads
  const int vb_ = (blockIdx.x & 7)*64 + (blockIdx.x >> 3);
  const int qblk = vb_ & 15, bh = vb_ >> 4;

  const int tid = threadIdx.x, w = tid >> 6, lane = tid & 63;
  const int g = lane >> 4, c16 = lane & 15;
  const int lr = lane >> 3, lg = lane & 7;
  const int gsrc = lg ^ (lr & 7);
  const int lr4 = lane >> 4, lg4 = lane & 15;

  __shared__ alignas(16) u16 klds[128*64];    // 16 KB
  __shared__ alignas(16) u16 vtlds[64*128];   // 16 KB
  __shared__ alignas(16) u16 plds[8*16*128];  // 32 KB (4 KB per warp)

  const u16* qsl = qb  + (size_t)bh*S_*DH;
  const u16* ksl = kb  + (size_t)bh*S_*DH;
  const u16* vsl = vtb + (size_t)bh*DH*S_;

  const int q0 = qblk*QBLK + w*16;
  bf16x8 qf[2];
  #pragma unroll
  for (int ks = 0; ks < 2; ++ks)
    qf[ks] = *(const bf16x8*)(qsl + (size_t)(q0 + c16)*DH + ks*32 + g*8);

  const float cl = (1.0f/32.0f)*1.44269504f;   // scale * log2(e)
  float sum = 0.f;

  auto stageK = [&](int kt){
    #pragma unroll
    for (int i = 0; i < 2; ++i){
      const int r = w*16 + i*8 + lr;
      gload16(ksl + (size_t)(kt + r)*DH + gsrc*8, klds + (w*16 + i*8)*64);
    }
  };
  auto stageV = [&](int kt){
    #pragma unroll
    for (int i = 0; i < 2; ++i){
      const int d = w*8 + i*4 + lr4;
      const int gs = lg4 ^ (d & 15);
      gload16(vsl + (size_t)d*S_ + kt + gs*8, vtlds + (w*8 + i*4)*128);
    }
  };

  // ---- pass 1: denominators ----
  for (int kt = 0; kt < S_; kt += KBLK){
    stageK(kt);
    __syncthreads();
    #pragma unroll
    for (int ng = 0; ng < 2; ++ng){
      bf16x8 kf[4][2];
      f32x4 s[4];
      #pragma unroll
      for (int j = 0; j < 4; ++j){
        const int krow = (ng*4 + j)*16 + c16;
        kf[j][0] = *(const bf16x8*)(klds + krow*64 + ((0 + g) ^ (krow & 7))*8);
        kf[j][1] = *(const bf16x8*)(klds + krow*64 + ((4 + g) ^ (krow & 7))*8);
      }
      __builtin_amdgcn_s_setprio(1);
      #pragma unroll
      for (int j = 0; j < 4; ++j){
        s[j] = (f32x4){0.f,0.f,0.f,0.f};
        s[j] = __builtin_amdgcn_mfma_f32_16x16x32_bf16(kf[j][0], qf[0], s[j], 0, 0, 0);
      }
      #pragma unroll
      for (int j = 0; j < 4; ++j)
        s[j] = __builtin_amdgcn_mfma_f32_16x16x32_bf16(kf[j][1], qf[1], s[j], 0, 0, 0);
      __builtin_amdgcn_s_setprio(0);
      #pragma unroll
      for (int j = 0; j < 4; ++j)
        #pragma unroll
        for (int r = 0; r < 4; ++r) sum += exp2f(s[j][r]*cl);
    }
    __syncthreads();
  }
  sum += __shfl_xor(sum, 16, 64);
  sum += __shfl_xor(sum, 32, 64);
  const float inv = 1.0f/sum;

  f32x4 oacc[4];
  #pragma unroll
  for (int n2 = 0; n2 < 4; ++n2) oacc[n2] = (f32x4){0.f,0.f,0.f,0.f};

  float* drow0 = dist + ((size_t)bh*S_ + q0)*S_;
  const int rlane = lane >> 5;          // 0/1: row within pair
  const int chunk = lane & 31;          // 4-float chunk within 128-col segment
  const int slotc = chunk >> 1, halfc = (chunk & 1)*4;

  // ---- pass 2: P -> plds, nt dist write (early), then PV ----
  for (int kt = 0; kt < S_; kt += KBLK){
    stageK(kt);
    stageV(kt);
    __syncthreads();
    #pragma unroll
    for (int ng = 0; ng < 2; ++ng){
      bf16x8 kf[4][2];
      f32x4 s[4];
      #pragma unroll
      for (int j = 0; j < 4; ++j){
        const int krow = (ng*4 + j)*16 + c16;
        kf[j][0] = *(const bf16x8*)(klds + krow*64 + ((0 + g) ^ (krow & 7))*8);
        kf[j][1] = *(const bf16x8*)(klds + krow*64 + ((4 + g) ^ (krow & 7))*8);
      }
      __builtin_amdgcn_s_setprio(1);
      #pragma unroll
      for (int j = 0; j < 4; ++j){
        s[j] = (f32x4){0.f,0.f,0.f,0.f};
        s[j] = __builtin_amdgcn_mfma_f32_16x16x32_bf16(kf[j][0], qf[0], s[j], 0, 0, 0);
      }
      #pragma unroll
      for (int j = 0; j < 4; ++j)
        s[j] = __builtin_amdgcn_mfma_f32_16x16x32_bf16(kf[j][1], qf[1], s[j], 0, 0, 0);
      __builtin_amdgcn_s_setprio(0);
      #pragma unroll
      for (int j = 0; j < 4; ++j){
        const int n = ng*4 + j;
        float p0 = exp2f(s[j][0]*cl)*inv, p1 = exp2f(s[j][1]*cl)*inv;
        float p2 = exp2f(s[j][2]*cl)*inv, p3 = exp2f(s[j][3]*cl)*inv;
        const int col = n*16 + g*4;
        const int slot = (col >> 3) ^ c16;
        unsigned lo = (unsigned)f2bf(p0) | ((unsigned)f2bf(p1) << 16);
        unsigned hi = (unsigned)f2bf(p2) | ((unsigned)f2bf(p3) << 16);
        uint2 pk2; pk2.x = lo; pk2.y = hi;
        *(uint2*)(plds + w*2048 + c16*128 + slot*8 + (g & 1)*4) = pk2;
      }
    }
    // coalesced nt dist write from plds — before PV so stores drain under MFMA
    #pragma unroll
    for (int it = 0; it < 8; ++it){
      const int row = it*2 + rlane;
      const u16* src = plds + w*2048 + row*128 + (slotc ^ row)*8 + halfc;
      uint2 pv = *(const uint2*)src;
      f32x4 o;
      o[0] = bf2f((u16)(pv.x & 0xffffu));
      o[1] = bf2f((u16)(pv.x >> 16));
      o[2] = bf2f((u16)(pv.y & 0xffffu));
      o[3] = bf2f((u16)(pv.y >> 16));
      __builtin_nontemporal_store(o, (f32x4*)(drow0 + (size_t)row*S_ + kt + chunk*4));
    }
    // PV: oacc += P @ V
    #pragma unroll
    for (int kc = 0; kc < 4; ++kc){
      bf16x8 pf = *(const bf16x8*)(plds + w*2048 + c16*128 + ((kc*4 + g) ^ c16)*8);
      __builtin_amdgcn_s_setprio(1);
      #pragma unroll
      for (int n2 = 0; n2 < 4; ++n2){
        const int d = n2*16 + c16;
        bf16x8 vf = *(const bf16x8*)(vtlds + d*128 + ((kc*4 + g) ^ (d & 15))*8);
        oacc[n2] = __builtin_amdgcn_mfma_f32_16x16x32_bf16(pf, vf, oacc[n2], 0, 0, 0);
      }
      __builtin_amdgcn_s_setprio(0);
    }
    __syncthreads();
  }

  u16* asl = attnb + (size_t)bh*S_*DH;
  #pragma unroll
  for (int n2 = 0; n2 < 4; ++n2)
    #pragma unroll
    for (int r = 0; r < 4; ++r)
      __builtin_nontemporal_store(f2bf(oacc[n2][r]),
          asl + (size_t)(q0 + g*4 + r)*DH + n2*16 + c16);
}

// ---------------- launch ----------------
extern "C" void kernel_launch(void* const* d_in, const int* in_sizes, int n_in,
                              void* d_out, int out_size, void* d_ws, size_t ws_size,
                              hipStream_t stream)
{
  const float* Q  = (const float*)d_in[0];
  const float* K  = (const float*)d_in[1];
  const float* V  = (const float*)d_in[2];
  const float* WQ = (const float*)d_in[3]; const float* bQ = (const float*)d_in[4];
  const float* WK = (const float*)d_in[5]; const float* bK = (const float*)d_in[6];
  const float* WV = (const float*)d_in[7]; const float* bV = (const float*)d_in[8];
  const float* WO = (const float*)d_in[9]; const float* bO = (const float*)d_in[10];

  float* out  = (float*)d_out;
  float* dist = out + (size_t)BS_*D_;

  char* ws = (char*)d_ws;
  u16* qb    = (u16*)(ws);
  u16* kb    = (u16*)(ws + (8u<<20));
  u16* vb    = (u16*)(ws + (16u<<20));
  u16* vtb   = (u16*)(ws + (24u<<20));
  u16* attnb = (u16*)(ws + (32u<<20));
  u16* wqb   = (u16*)(ws + (40u<<20));
  u16* wkb   = (u16*)(ws + (42u<<20));
  u16* wvb   = (u16*)(ws + (44u<<20));
  u16* wob   = (u16*)(ws + (46u<<20));

  cvt_kernel<<<2048, 256, 0, stream>>>(WQ, WK, WV, WO, wqb, wkb, wvb, wob);

  qkv_gemm_kernel<<<dim3(BS_/128, D_/128, 3), 256, 0, stream>>>(
      Q, K, V, wqb, wkb, wvb, bQ, bK, bV, qb, kb, vb);

  vtrans_kernel<<<dim3(S_/64, B_*H_), 256, 0, stream>>>(vb, vtb);

  attn_kernel<<<dim3((S_/QBLK)*(B_*H_)), 512, 0, stream>>>(qb, kb, vtb, dist, attnb);

  out_gemm_kernel<<<dim3(BS_/128, D_/128), 256, 0, stream>>>(attnb, wob, bO, out);
}

// Round 12
// 226.138 us; speedup vs baseline: 1.1588x; 1.0505x over previous
//
#include <hip/hip_runtime.h>
#include <stdint.h>

#define B_ 2
#define S_ 2048
#define D_ 1024
#define H_ 16
#define DH 64
#define BS_ (B_*S_)
#define QBLK 128
#define KBLK 128

typedef unsigned short u16;
typedef __attribute__((ext_vector_type(8))) __bf16 bf16x8;
typedef __attribute__((ext_vector_type(4))) float f32x4;

__device__ __forceinline__ u16 f2bf(float f){
  unsigned u = __float_as_uint(f);
  u += 0x7fffu + ((u >> 16) & 1u);   // RNE
  return (u16)(u >> 16);
}
__device__ __forceinline__ float bf2f(u16 v){
  return __uint_as_float(((unsigned)v) << 16);
}

union pk8 { u16 a[8]; uint4 v; };

typedef __attribute__((address_space(1))) const unsigned gas_u32;
typedef __attribute__((address_space(3))) unsigned las_u32;
__device__ __forceinline__ void gload16(const void* g, void* l){
  __builtin_amdgcn_global_load_lds((gas_u32*)g, (las_u32*)l, 16, 0, 0);
}

// ---------------- fp32 -> bf16 bulk convert (7 tensors), nt loads ----------------
__global__ __launch_bounds__(256) void cvt_kernel(
    const float* __restrict__ Q, const float* __restrict__ K, const float* __restrict__ V,
    const float* __restrict__ WQ, const float* __restrict__ WK,
    const float* __restrict__ WV, const float* __restrict__ WO,
    u16* Qc, u16* Kc, u16* Vc, u16* wq, u16* wk, u16* wv, u16* wo)
{
  const int b = blockIdx.x;
  const float* s; u16* d; size_t off;
  if (b < 6144){
    int t = b >> 11;
    s = t==0?Q:(t==1?K:V); d = t==0?Qc:(t==1?Kc:Vc);
    off = (size_t)(b & 2047)*2048;
  } else {
    int t = (b - 6144) >> 9;
    s = t==0?WQ:(t==1?WK:(t==2?WV:WO)); d = t==0?wq:(t==1?wk:(t==2?wv:wo));
    off = (size_t)((b - 6144) & 511)*2048;
  }
  const float* sp = s + off + (size_t)threadIdx.x*8;
  f32x4 v0 = __builtin_nontemporal_load((const f32x4*)sp);
  f32x4 v1 = __builtin_nontemporal_load((const f32x4*)(sp + 4));
  pk8 p;
  p.a[0]=f2bf(v0[0]); p.a[1]=f2bf(v0[1]); p.a[2]=f2bf(v0[2]); p.a[3]=f2bf(v0[3]);
  p.a[4]=f2bf(v1[0]); p.a[5]=f2bf(v1[1]); p.a[6]=f2bf(v1[2]); p.a[7]=f2bf(v1[3]);
  *(uint4*)(d + off + (size_t)threadIdx.x*8) = p.v;
}

// ---------------- GEMM core (device) -------------------------------------
template<int F32OUT>
__device__ __forceinline__ void gemm_body(
    const u16* __restrict__ A, const u16* __restrict__ Wt,
    const float* __restrict__ bias, void* __restrict__ Cout,
    int bm, int bn, int N, int K)
{
  const int tid = threadIdx.x, w = tid >> 6, lane = tid & 63;
  const int g = lane >> 4, c16 = lane & 15;
  const int wr = w >> 1, wc = w & 1;
  const int lr = lane >> 3, lg = lane & 7;
  const int gsrc = lg ^ (lr & 7);

  __shared__ alignas(16) u16 at[2][128*64];
  __shared__ alignas(16) u16 bt[2][128*64];

  f32x4 acc[4][4];
  #pragma unroll
  for (int mi = 0; mi < 4; ++mi)
    #pragma unroll
    for (int ni = 0; ni < 4; ++ni) acc[mi][ni] = (f32x4){0.f,0.f,0.f,0.f};

  auto stage = [&](int buf, int kt){
    #pragma unroll
    for (int i = 0; i < 4; ++i){
      const int r = w*32 + i*8 + lr;
      gload16(A + (size_t)(bm*128 + r)*K + kt + gsrc*8, at[buf] + (w*32 + i*8)*64);
    }
    #pragma unroll
    for (int i = 0; i < 4; ++i){
      const int r = w*32 + i*8 + lr;
      gload16(Wt + (size_t)(bn*128 + r)*K + kt + gsrc*8, bt[buf] + (w*32 + i*8)*64);
    }
  };

  stage(0, 0);
  __syncthreads();
  int cur = 0;
  for (int kt = 0; kt < K; kt += 64){
    if (kt + 64 < K) stage(cur ^ 1, kt + 64);
    #pragma unroll
    for (int ks = 0; ks < 2; ++ks){
      bf16x8 af[4], bfr[4];
      #pragma unroll
      for (int mi = 0; mi < 4; ++mi){
        const int row = wr*64 + mi*16 + c16;
        af[mi] = *(const bf16x8*)(at[cur] + row*64 + ((ks*4 + g) ^ (row & 7))*8);
      }
      #pragma unroll
      for (int ni = 0; ni < 4; ++ni){
        const int row = wc*64 + ni*16 + c16;
        bfr[ni] = *(const bf16x8*)(bt[cur] + row*64 + ((ks*4 + g) ^ (row & 7))*8);
      }
      #pragma unroll
      for (int mi = 0; mi < 4; ++mi)
        #pragma unroll
        for (int ni = 0; ni < 4; ++ni)
          acc[mi][ni] = __builtin_amdgcn_mfma_f32_16x16x32_bf16(
              af[mi], bfr[ni], acc[mi][ni], 0, 0, 0);
    }
    __syncthreads();
    cur ^= 1;
  }

  #pragma unroll
  for (int mi = 0; mi < 4; ++mi){
    const int row0 = bm*128 + wr*64 + mi*16 + g*4;
    #pragma unroll
    for (int ni = 0; ni < 4; ++ni){
      const int col = bn*128 + wc*64 + ni*16 + c16;
      const float bb = bias[col];
      #pragma unroll
      for (int r = 0; r < 4; ++r){
        float v = acc[mi][ni][r] + bb;
        if (F32OUT) __builtin_nontemporal_store(v, (float*)Cout + (size_t)(row0 + r)*N + col);
        else        ((u16*)Cout)[(size_t)(row0 + r)*N + col] = f2bf(v);
      }
    }
  }
}

__global__ __launch_bounds__(256) void qkv_gemm_kernel(
    const u16* __restrict__ A0, const u16* __restrict__ A1, const u16* __restrict__ A2,
    const u16* __restrict__ W0, const u16* __restrict__ W1, const u16* __restrict__ W2,
    const float* __restrict__ b0, const float* __restrict__ b1, const float* __restrict__ b2,
    u16* C0, u16* C1, u16* C2)
{
  const int t = blockIdx.z;
  const u16* A = t==0?A0:(t==1?A1:A2);
  const u16* W = t==0?W0:(t==1?W1:W2);
  const float* bb = t==0?b0:(t==1?b1:b2);
  u16* C = t==0?C0:(t==1?C1:C2);
  gemm_body<0>(A, W, bb, C, blockIdx.x, blockIdx.y, D_, D_);
}

__global__ __launch_bounds__(256) void out_gemm_kernel(
    const u16* __restrict__ A, const u16* __restrict__ W,
    const float* __restrict__ bias, float* __restrict__ C)
{
  gemm_body<1>(A, W, bias, C, blockIdx.x, blockIdx.y, D_, D_);
}

// ---------------- per-head V transpose: vtb[bh][d][k] = vb[bh][k][d] ----------------
__global__ __launch_bounds__(256) void vtrans_kernel(
    const u16* __restrict__ vb, u16* __restrict__ vtb)
{
  const int kt = blockIdx.x, bh = blockIdx.y;
  __shared__ alignas(16) u16 t[64][80];
  const int tid = threadIdx.x;
  const u16* slab = vb + (size_t)bh*S_*DH + (size_t)kt*64*DH;
  #pragma unroll
  for (int j = 0; j < 2; ++j){
    const int r = j*32 + (tid >> 3), c = (tid & 7)*8;
    *(bf16x8*)(&t[r][c]) = *(const bf16x8*)(slab + (size_t)r*DH + c);
  }
  __syncthreads();
  u16* oslab = vtb + (size_t)bh*DH*S_ + (size_t)kt*64;
  #pragma unroll
  for (int j = 0; j < 2; ++j){
    const int dd = j*32 + (tid >> 3), k8 = (tid & 7)*8;
    pk8 u;
    #pragma unroll
    for (int e = 0; e < 8; ++e) u.a[e] = t[k8 + e][dd];
    *(uint4*)(oslab + (size_t)dd*S_ + k8) = u.v;
  }
}

// ---------------- fused attention: QBLK=128, 8 waves, nt dist writes ------
// Unified 64 KB LDS: [KV 32 KB][plds 32 KB].
// pass 1 stages 256 K-rows per barrier-pair (KV region whole);
// pass 2: klds = KV[0:128 rows], vtlds = KV+8192, plds = smem+16384.
__global__ __launch_bounds__(512, 4) void attn_kernel(
    const u16* __restrict__ qb, const u16* __restrict__ kb,
    const u16* __restrict__ vtb, float* __restrict__ dist,
    u16* __restrict__ attnb)
{
  // bijective remap: XCD (blockIdx.x%8) owns 4 consecutive heads
  const int vb_ = (blockIdx.x & 7)*64 + (blockIdx.x >> 3);
  const int qblk = vb_ & 15, bh = vb_ >> 4;

  const int tid = threadIdx.x, w = tid >> 6, lane = tid & 63;
  const int g = lane >> 4, c16 = lane & 15;
  const int lr = lane >> 3, lg = lane & 7;
  const int gsrc = lg ^ (lr & 7);
  const int lr4 = lane >> 4, lg4 = lane & 15;

  __shared__ alignas(16) u16 smem[32768];     // 64 KB
  u16* kv   = smem;                            // pass1: 256x64; pass2: klds 128x64
  u16* vt   = smem + 8192;                     // pass2: vtlds 64x128
  u16* plds = smem + 16384;                    // 8 waves x 16 x 128

  const u16* qsl = qb  + (size_t)bh*S_*DH;
  const u16* ksl = kb  + (size_t)bh*S_*DH;
  const u16* vsl = vtb + (size_t)bh*DH*S_;

  const int q0 = qblk*QBLK + w*16;
  bf16x8 qf[2];
  #pragma unroll
  for (int ks = 0; ks < 2; ++ks)
    qf[ks] = *(const bf16x8*)(qsl + (size_t)(q0 + c16)*DH + ks*32 + g*8);

  const float cl = (1.0f/32.0f)*1.44269504f;   // scale * log2(e)
  float sum = 0.f;

  // ---- pass 1: denominators, 256-row K tiles ----
  for (int kt = 0; kt < S_; kt += 256){
    #pragma unroll
    for (int i = 0; i < 4; ++i){
      const int r = w*32 + i*8 + lr;
      gload16(ksl + (size_t)(kt + r)*DH + gsrc*8, kv + (w*32 + i*8)*64);
    }
    __syncthreads();
    #pragma unroll
    for (int ng = 0; ng < 4; ++ng){
      bf16x8 kf[4][2];
      f32x4 s[4];
      #pragma unroll
      for (int j = 0; j < 4; ++j){
        const int krow = (ng*4 + j)*16 + c16;
        kf[j][0] = *(const bf16x8*)(kv + krow*64 + ((0 + g) ^ (krow & 7))*8);
        kf[j][1] = *(const bf16x8*)(kv + krow*64 + ((4 + g) ^ (krow & 7))*8);
      }
      __builtin_amdgcn_s_setprio(1);
      #pragma unroll
      for (int j = 0; j < 4; ++j){
        s[j] = (f32x4){0.f,0.f,0.f,0.f};
        s[j] = __builtin_amdgcn_mfma_f32_16x16x32_bf16(kf[j][0], qf[0], s[j], 0, 0, 0);
      }
      #pragma unroll
      for (int j = 0; j < 4; ++j)
        s[j] = __builtin_amdgcn_mfma_f32_16x16x32_bf16(kf[j][1], qf[1], s[j], 0, 0, 0);
      __builtin_amdgcn_s_setprio(0);
      #pragma unroll
      for (int j = 0; j < 4; ++j)
        #pragma unroll
        for (int r = 0; r < 4; ++r) sum += exp2f(s[j][r]*cl);
    }
    __syncthreads();
  }
  sum += __shfl_xor(sum, 16, 64);
  sum += __shfl_xor(sum, 32, 64);
  const float inv = 1.0f/sum;

  f32x4 oacc[4];
  #pragma unroll
  for (int n2 = 0; n2 < 4; ++n2) oacc[n2] = (f32x4){0.f,0.f,0.f,0.f};

  float* drow0 = dist + ((size_t)bh*S_ + q0)*S_;
  const int rlane = lane >> 5;          // 0/1: row within pair
  const int chunk = lane & 31;          // 4-float chunk within 128-col segment
  const int slotc = chunk >> 1, halfc = (chunk & 1)*4;

  // ---- pass 2: P -> plds, nt dist write (early), then PV ----
  for (int kt = 0; kt < S_; kt += KBLK){
    #pragma unroll
    for (int i = 0; i < 2; ++i){
      const int r = w*16 + i*8 + lr;
      gload16(ksl + (size_t)(kt + r)*DH + gsrc*8, kv + (w*16 + i*8)*64);
    }
    #pragma unroll
    for (int i = 0; i < 2; ++i){
      const int d = w*8 + i*4 + lr4;
      const int gs = lg4 ^ (d & 15);
      gload16(vsl + (size_t)d*S_ + kt + gs*8, vt + (w*8 + i*4)*128);
    }
    __syncthreads();
    #pragma unroll
    for (int ng = 0; ng < 2; ++ng){
      bf16x8 kf[4][2];
      f32x4 s[4];
      #pragma unroll
      for (int j = 0; j < 4; ++j){
        const int krow = (ng*4 + j)*16 + c16;
        kf[j][0] = *(const bf16x8*)(kv + krow*64 + ((0 + g) ^ (krow & 7))*8);
        kf[j][1] = *(const bf16x8*)(kv + krow*64 + ((4 + g) ^ (krow & 7))*8);
      }
      __builtin_amdgcn_s_setprio(1);
      #pragma unroll
      for (int j = 0; j < 4; ++j){
        s[j] = (f32x4){0.f,0.f,0.f,0.f};
        s[j] = __builtin_amdgcn_mfma_f32_16x16x32_bf16(kf[j][0], qf[0], s[j], 0, 0, 0);
      }
      #pragma unroll
      for (int j = 0; j < 4; ++j)
        s[j] = __builtin_amdgcn_mfma_f32_16x16x32_bf16(kf[j][1], qf[1], s[j], 0, 0, 0);
      __builtin_amdgcn_s_setprio(0);
      #pragma unroll
      for (int j = 0; j < 4; ++j){
        const int n = ng*4 + j;
        float p0 = exp2f(s[j][0]*cl)*inv, p1 = exp2f(s[j][1]*cl)*inv;
        float p2 = exp2f(s[j][2]*cl)*inv, p3 = exp2f(s[j][3]*cl)*inv;
        const int col = n*16 + g*4;
        const int slot = (col >> 3) ^ c16;
        unsigned lo = (unsigned)f2bf(p0) | ((unsigned)f2bf(p1) << 16);
        unsigned hi = (unsigned)f2bf(p2) | ((unsigned)f2bf(p3) << 16);
        uint2 pk2; pk2.x = lo; pk2.y = hi;
        *(uint2*)(plds + w*2048 + c16*128 + slot*8 + (g & 1)*4) = pk2;
      }
    }
    // coalesced nt dist write from plds — before PV so stores drain under MFMA
    #pragma unroll
    for (int it = 0; it < 8; ++it){
      const int row = it*2 + rlane;
      const u16* src = plds + w*2048 + row*128 + (slotc ^ row)*8 + halfc;
      uint2 pv = *(const uint2*)src;
      f32x4 o;
      o[0] = bf2f((u16)(pv.x & 0xffffu));
      o[1] = bf2f((u16)(pv.x >> 16));
      o[2] = bf2f((u16)(pv.y & 0xffffu));
      o[3] = bf2f((u16)(pv.y >> 16));
      __builtin_nontemporal_store(o, (f32x4*)(drow0 + (size_t)row*S_ + kt + chunk*4));
    }
    // PV: oacc += P @ V
    #pragma unroll
    for (int kc = 0; kc < 4; ++kc){
      bf16x8 pf = *(const bf16x8*)(plds + w*2048 + c16*128 + ((kc*4 + g) ^ c16)*8);
      __builtin_amdgcn_s_setprio(1);
      #pragma unroll
      for (int n2 = 0; n2 < 4; ++n2){
        const int d = n2*16 + c16;
        bf16x8 vf = *(const bf16x8*)(vt + d*128 + ((kc*4 + g) ^ (d & 15))*8);
        oacc[n2] = __builtin_amdgcn_mfma_f32_16x16x32_bf16(pf, vf, oacc[n2], 0, 0, 0);
      }
      __builtin_amdgcn_s_setprio(0);
    }
    __syncthreads();
  }

  u16* asl = attnb + (size_t)bh*S_*DH;
  #pragma unroll
  for (int n2 = 0; n2 < 4; ++n2)
    #pragma unroll
    for (int r = 0; r < 4; ++r)
      __builtin_nontemporal_store(f2bf(oacc[n2][r]),
          asl + (size_t)(q0 + g*4 + r)*DH + n2*16 + c16);
}

// ---------------- launch ----------------
extern "C" void kernel_launch(void* const* d_in, const int* in_sizes, int n_in,
                              void* d_out, int out_size, void* d_ws, size_t ws_size,
                              hipStream_t stream)
{
  const float* Q  = (const float*)d_in[0];
  const float* K  = (const float*)d_in[1];
  const float* V  = (const float*)d_in[2];
  const float* WQ = (const float*)d_in[3]; const float* bQ = (const float*)d_in[4];
  const float* WK = (const float*)d_in[5]; const float* bK = (const float*)d_in[6];
  const float* WV = (const float*)d_in[7]; const float* bV = (const float*)d_in[8];
  const float* WO = (const float*)d_in[9]; const float* bO = (const float*)d_in[10];

  float* out  = (float*)d_out;
  float* dist = out + (size_t)BS_*D_;

  char* ws = (char*)d_ws;
  u16* qb    = (u16*)(ws);
  u16* kb    = (u16*)(ws + (8u<<20));
  u16* vb    = (u16*)(ws + (16u<<20));
  u16* vtb   = (u16*)(ws + (24u<<20));
  u16* attnb = (u16*)(ws + (32u<<20));
  u16* Qc    = (u16*)(ws + (40u<<20));
  u16* Kc    = (u16*)(ws + (48u<<20));
  u16* Vc    = (u16*)(ws + (56u<<20));
  u16* wqb   = (u16*)(ws + (64u<<20));
  u16* wkb   = (u16*)(ws + (66u<<20));
  u16* wvb   = (u16*)(ws + (68u<<20));
  u16* wob   = (u16*)(ws + (70u<<20));

  cvt_kernel<<<8192, 256, 0, stream>>>(Q, K, V, WQ, WK, WV, WO,
                                       Qc, Kc, Vc, wqb, wkb, wvb, wob);

  qkv_gemm_kernel<<<dim3(BS_/128, D_/128, 3), 256, 0, stream>>>(
      Qc, Kc, Vc, wqb, wkb, wvb, bQ, bK, bV, qb, kb, vb);

  vtrans_kernel<<<dim3(S_/64, B_*H_), 256, 0, stream>>>(vb, vtb);

  attn_kernel<<<dim3((S_/QBLK)*(B_*H_)), 512, 0, stream>>>(qb, kb, vtb, dist, attnb);

  out_gemm_kernel<<<dim3(BS_/128, D_/128), 256, 0, stream>>>(attnb, wob, bO, out);
}